// Round 10
// baseline (21175.259 us; speedup 1.0000x reference)
//
#include <hip/hip_runtime.h>
#include <math.h>

#define NTHR 1024

// per-batch global e-buffers (floats)
constexpr int E1_OFF  = 0;          // level 1: 128 rows x 128
constexpr int E2_OFF  = 16384;      // level 2: 64 rows
constexpr int E3_OFF  = 24576;      // level 3: 32 rows
constexpr int E4_OFF  = 28672;      // level 4: 16 rows
constexpr int EG_STRIDE = 30720;    // floats per batch

__device__ __forceinline__ int xoff(int l) { return 512 - (512 >> l); }   // l in 0..7
// LDS e-levels 5..8 offsets (floats): rows 8,4,2,1(+pad)
__device__ __forceinline__ int ldse(int l) {
  return (l == 5) ? 0 : (l == 6) ? 1024 : (l == 7) ? 1536 : 1792;
}

// ---- one MLP chunk: eout = relu(z@W1+b1 [+lab]) @ W2 + b2 ----------------
// 16 waves = 16 K-slices of 16k (both layers). L1: lane owns 4 cols and
// preloads its whole 16x4 weight slice into float4 w[16] (64 VGPRs, 16
// independent b128 loads in flight -> one latency exposure per phase).
// L2: lane owns 2 cols, float2 w[16]. Weights read exactly once per chunk.
// z/h reads are wave-uniform LDS/global broadcasts (amp-1).
// NOTE: needs ~100 VGPRs live -> __launch_bounds__(1024,1) (cap 128).
template <int C, bool ZG>
__device__ __forceinline__ void mlp_chunk(
    const float* __restrict__ zg, const float* zl, int zstr,
    const float* __restrict__ W1, const float* __restrict__ B1,
    const float* __restrict__ W2, const float* __restrict__ B2,
    const float* lab, bool uselab, const int* u1h, int done,
    float* red, float* h, float* eoutL, float* __restrict__ eoutG)
{
  const int t  = threadIdx.x;
  const int wv = t >> 6;          // K-slice 0..15  (k in [16wv,16wv+16))
  const int ln = t & 63;
  // -------- layer-1 partials --------
  {
    const int k0 = 16 * wv;
    const int c0 = 4 * ln;
    float4 w[16];
#pragma unroll
    for (int j = 0; j < 16; ++j)
      w[j] = *reinterpret_cast<const float4*>(W1 + (k0 + j) * 256 + c0);
#pragma unroll 1
    for (int r = 0; r < C; ++r) {
      float4 z4[4];
#pragma unroll
      for (int j = 0; j < 4; ++j) {
        if (ZG) z4[j] = *reinterpret_cast<const float4*>(zg + r * zstr + k0 + 4 * j);
        else    z4[j] = *reinterpret_cast<const float4*>(zl + r * zstr + k0 + 4 * j);
      }
      float4 acc = make_float4(0.f, 0.f, 0.f, 0.f);
#pragma unroll
      for (int j = 0; j < 4; ++j) {
        acc.x = fmaf(z4[j].x, w[4*j+0].x, fmaf(z4[j].y, w[4*j+1].x,
                fmaf(z4[j].z, w[4*j+2].x, fmaf(z4[j].w, w[4*j+3].x, acc.x))));
        acc.y = fmaf(z4[j].x, w[4*j+0].y, fmaf(z4[j].y, w[4*j+1].y,
                fmaf(z4[j].z, w[4*j+2].y, fmaf(z4[j].w, w[4*j+3].y, acc.y))));
        acc.z = fmaf(z4[j].x, w[4*j+0].z, fmaf(z4[j].y, w[4*j+1].z,
                fmaf(z4[j].z, w[4*j+2].z, fmaf(z4[j].w, w[4*j+3].z, acc.z))));
        acc.w = fmaf(z4[j].x, w[4*j+0].w, fmaf(z4[j].y, w[4*j+1].w,
                fmaf(z4[j].z, w[4*j+2].w, fmaf(z4[j].w, w[4*j+3].w, acc.w))));
      }
      *reinterpret_cast<float4*>(red + (wv * C + r) * 256 + c0) = acc;
    }
  }
  __syncthreads();
  // -------- layer-1 reduce + bias + lab + relu -> h --------
  if (t < 64 * C) {
    const int r  = t >> 6;
    const int c0 = 4 * (t & 63);
    float4 s = *reinterpret_cast<const float4*>(B1 + c0);
    if (uselab) {
      const int j = u1h[done + r] & 1;
      const float4 lv = *reinterpret_cast<const float4*>(lab + j * 256 + c0);
      s.x += lv.x; s.y += lv.y; s.z += lv.z; s.w += lv.w;
    }
#pragma unroll
    for (int q = 0; q < 16; ++q) {
      const float4 p = *reinterpret_cast<const float4*>(red + (q * C + r) * 256 + c0);
      s.x += p.x; s.y += p.y; s.z += p.z; s.w += p.w;
    }
    s.x = fmaxf(s.x, 0.f); s.y = fmaxf(s.y, 0.f);
    s.z = fmaxf(s.z, 0.f); s.w = fmaxf(s.w, 0.f);
    *reinterpret_cast<float4*>(h + r * 256 + c0) = s;
  }
  __syncthreads();
  // -------- layer-2 partials --------
  {
    const int k0 = 16 * wv;
    const int c0 = 2 * ln;
    float2 w[16];
#pragma unroll
    for (int j = 0; j < 16; ++j)
      w[j] = *reinterpret_cast<const float2*>(W2 + (k0 + j) * 128 + c0);
#pragma unroll 1
    for (int r = 0; r < C; ++r) {
      float4 h4[4];
#pragma unroll
      for (int j = 0; j < 4; ++j)
        h4[j] = *reinterpret_cast<const float4*>(h + r * 256 + k0 + 4 * j);
      float2 acc = make_float2(0.f, 0.f);
#pragma unroll
      for (int j = 0; j < 4; ++j) {
        acc.x = fmaf(h4[j].x, w[4*j+0].x, fmaf(h4[j].y, w[4*j+1].x,
                fmaf(h4[j].z, w[4*j+2].x, fmaf(h4[j].w, w[4*j+3].x, acc.x))));
        acc.y = fmaf(h4[j].x, w[4*j+0].y, fmaf(h4[j].y, w[4*j+1].y,
                fmaf(h4[j].z, w[4*j+2].y, fmaf(h4[j].w, w[4*j+3].y, acc.y))));
      }
      *reinterpret_cast<float2*>(red + (wv * C + r) * 128 + c0) = acc;
    }
  }
  __syncthreads();
  // -------- layer-2 reduce + bias -> eout --------
  if (t < 128 * C) {
    const int r = t >> 7;
    const int c = t & 127;
    float s = B2[c];
#pragma unroll
    for (int q = 0; q < 16; ++q) s += red[(q * C + r) * 128 + c];
    if (eoutL) eoutL[r * 128 + c] = s;
    else       eoutG[r * 128 + c] = s;
  }
  __syncthreads();
}

__global__ void sc_setup(const int* __restrict__ info_set,
                         const float* __restrict__ E_obs,
                         const float* __restrict__ E_lab,
                         const float* __restrict__ Wb1,
                         int* __restrict__ pos2k, float* __restrict__ lab1,
                         float* __restrict__ eroot)
{
  const int t = threadIdx.x;   // 256 threads
  pos2k[t] = -1;
  __syncthreads();
  if (t < 128) pos2k[info_set[t]] = t;
  eroot[t] = E_obs[2 * 128 + (t & 127)];
  for (int j = 0; j < 2; ++j) {
    float s = 0.0f;
    for (int k = 0; k < 128; ++k)
      s = fmaf(E_lab[j * 128 + k], Wb1[(256 + k) * 256 + t], s);
    lab1[j * 256 + t] = s;
  }
}

__global__ __launch_bounds__(NTHR, 1)
void sc_main(const int* __restrict__ info_bits, const float* __restrict__ rin,
             const float* __restrict__ Wc1, const float* __restrict__ bc1,
             const float* __restrict__ Wc2, const float* __restrict__ bc2,
             const float* __restrict__ Wb1, const float* __restrict__ bb1,
             const float* __restrict__ Wb2, const float* __restrict__ bb2,
             const float* __restrict__ Wl, const float* __restrict__ bl,
             const int* __restrict__ pos2k, const float* __restrict__ lab1_g,
             const float* __restrict__ eroot_g,
             float* __restrict__ wsall, float* __restrict__ out)
{
  const int b = blockIdx.x;
  const int t = threadIdx.x;
  float* eg = wsall + (size_t)b * EG_STRIDE;   // levels 1..4 (global)

  __shared__ float red[32768];      // 128 KB split-K partials
  __shared__ float h_lds[2048];     //   8 KB hidden
  __shared__ float e_lds[2048];     //   8 KB e-levels 5..8 (+pad)
  __shared__ float lab_lds[512];
  __shared__ float eroot[256];
  __shared__ int   xh[520];         // +8 pad (padded-row u1h reads)

  for (int idx = t; idx < 512; idx += NTHR) lab_lds[idx] = lab1_g[idx];
  if (t < 256) eroot[t] = eroot_g[t];
  if (t >= 512 && t < 520) xh[t] = 0;
  __syncthreads();

  float* xO = out;
  float* fO = out + 32768;
  float* uO = out + 65536;
  float* pO = out + 98304;
  float* rO = out + 131072;

  auto run_level = [&](int l, bool isbit) {
    const int rows = 128 >> l;
    const float* W1 = isbit ? Wb1 : Wc1;
    const float* B1 = isbit ? bb1 : bc1;
    const float* W2 = isbit ? Wb2 : Wc2;
    const float* B2 = isbit ? bb2 : bc2;
    const int* u1h = xh + xoff(l);
    const float* zg = nullptr; const float* zl = nullptr;
    int zstr = 256; bool isZG = false;
    float* eoL = nullptr; float* eoG = nullptr;
    switch (l) {
      case 0: zl = eroot; zstr = 0;            eoG = eg + E1_OFF; break;
      case 1: zg = eg + E1_OFF; isZG = true;   eoG = eg + E2_OFF; break;
      case 2: zg = eg + E2_OFF; isZG = true;   eoG = eg + E3_OFF; break;
      case 3: zg = eg + E3_OFF; isZG = true;   eoG = eg + E4_OFF; break;
      case 4: zg = eg + E4_OFF; isZG = true;   eoL = e_lds + ldse(5); break;
      case 5: zl = e_lds + ldse(5);            eoL = e_lds + ldse(6); break;
      case 6: zl = e_lds + ldse(6);            eoL = e_lds + ldse(7); break;
      default: zl = e_lds + ldse(7);           eoL = e_lds + ldse(8); break;
    }
    int done = 0;
    while (done < rows) {
      int c = rows - done;
      if (c > 8) c = 8;
      const float* zgc = zg ? zg + done * zstr : nullptr;
      const float* zlc = zl ? zl + done * zstr : nullptr;
      float* eoLc = eoL ? eoL + done * 128 : nullptr;
      float* eoGc = eoG ? eoG + done * 128 : nullptr;
      if (c == 8) {
        if (isZG) mlp_chunk<8, true >(zgc, zlc, zstr, W1, B1, W2, B2, lab_lds, isbit, u1h, done, red, h_lds, eoLc, eoGc);
        else      mlp_chunk<8, false>(zgc, zlc, zstr, W1, B1, W2, B2, lab_lds, isbit, u1h, done, red, h_lds, eoLc, eoGc);
      } else if (c == 4) {
        if (isZG) mlp_chunk<4, true >(zgc, zlc, zstr, W1, B1, W2, B2, lab_lds, isbit, u1h, done, red, h_lds, eoLc, eoGc);
        else      mlp_chunk<4, false>(zgc, zlc, zstr, W1, B1, W2, B2, lab_lds, isbit, u1h, done, red, h_lds, eoLc, eoGc);
      } else {    // c == 2 or 1 -> padded C=2
        if (isZG) mlp_chunk<2, true >(zgc, zlc, zstr, W1, B1, W2, B2, lab_lds, isbit, u1h, done, red, h_lds, eoLc, eoGc);
        else      mlp_chunk<2, false>(zgc, zlc, zstr, W1, B1, W2, B2, lab_lds, isbit, u1h, done, red, h_lds, eoLc, eoGc);
      }
      done += c;
    }
  };

  auto do_leaf = [&](int i) {
    const float* e = e_lds + ldse(8);
    if (t < 64) {
      float partial = e[t] * Wl[t] + e[t + 64] * Wl[t + 64];
#pragma unroll
      for (int m = 32; m >= 1; m >>= 1) partial += __shfl_xor(partial, m);
      if (t == 0) {
        const float tv = partial + bl[0];
        const float p  = 1.0f / (1.0f + expf(-tv));
        const float rv = rin[b * 256 + i];
        const int  hd     = (rv > p) ? 1 : 0;
        const bool frozen = fabsf(p - 0.5f) > 0.25f;
        const int  k  = pos2k[i];
        const int  fc = (k >= 0) ? info_bits[b * 128 + k] : 2;
        const int  x  = (fc == 2 || frozen) ? hd : fc;
        xh[xoff(7) + (i & 1)] = x;
        pO[b * 256 + i] = p;
        uO[b * 256 + i] = (float)x;
        fO[b * 256 + i] = (k >= 0) ? 2.0f : 1.0f;
        rO[b * 256 + i] = rv;
      }
    }
    __syncthreads();
  };
  auto do_combine = [&](int l, int side) {
    const int n = 256 >> l, half = n >> 1;
    if (t < half) {
      const int u1 = xh[xoff(l) + t];
      const int u2 = xh[xoff(l) + half + t];
      if (l > 0) {
        const int base = xoff(l - 1) + side * n;
        xh[base + 2 * t]     = u1 ^ u2;
        xh[base + 2 * t + 1] = u2;
      } else {
        xO[b * 256 + 2 * t]     = (float)(u1 ^ u2);
        xO[b * 256 + 2 * t + 1] = (float)u2;
      }
    }
    __syncthreads();
  };

  // ---- SC traversal, single stage call-site ----
  int i = 0, l = 0;
  bool isbit = false;
  while (true) {
    run_level(l, isbit);
    if (l < 7) { ++l; isbit = false; continue; }
    do_leaf(i);
    if (i == 255) break;
    ++i;
    const int s = __builtin_ctz(i);
    for (int j = 1; j <= s; ++j) do_combine(8 - j, (j < s) ? 1 : 0);
    l = 7 - s;
    isbit = true;
  }
  for (int j = 1; j <= 8; ++j) do_combine(8 - j, 1);
}

extern "C" void kernel_launch(void* const* d_in, const int* in_sizes, int n_in,
                              void* d_out, int out_size, void* d_ws, size_t ws_size,
                              hipStream_t stream)
{
  const int*   info_bits = (const int*)  d_in[0];
  const float* rin       = (const float*)d_in[1];
  const int*   info_set  = (const int*)  d_in[2];
  const float* E_obs     = (const float*)d_in[3];
  const float* E_lab     = (const float*)d_in[4];
  const float* Wc1 = (const float*)d_in[5];
  const float* bc1 = (const float*)d_in[6];
  const float* Wc2 = (const float*)d_in[7];
  const float* bc2 = (const float*)d_in[8];
  const float* Wb1 = (const float*)d_in[9];
  const float* bb1 = (const float*)d_in[10];
  const float* Wb2 = (const float*)d_in[11];
  const float* bb2 = (const float*)d_in[12];
  const float* Wl  = (const float*)d_in[13];
  const float* bl  = (const float*)d_in[14];

  int*   pos2k = (int*)d_ws;                 // 256 ints
  float* lab1  = (float*)d_ws + 256;         // 512 floats
  float* eroot = (float*)d_ws + 768;         // 256 floats
  float* wsall = (float*)d_ws + 1024;        // 128 x EG_STRIDE floats

  hipLaunchKernelGGL(sc_setup, dim3(1), dim3(256), 0, stream,
                     info_set, E_obs, E_lab, Wb1, pos2k, lab1, eroot);
  hipLaunchKernelGGL(sc_main, dim3(128), dim3(NTHR), 0, stream,
                     info_bits, rin,
                     Wc1, bc1, Wc2, bc2, Wb1, bb1, Wb2, bb2, Wl, bl,
                     pos2k, lab1, eroot, wsall, (float*)d_out);
}

// Round 11
// 4594.179 us; speedup vs baseline: 4.6091x; 4.6091x over previous
//
#include <hip/hip_runtime.h>
#include <math.h>

#define NTHR 512

// per-batch global e-buffers (floats)
constexpr int E1_OFF  = 0;          // level 1: 128 rows x 128
constexpr int E2_OFF  = 16384;      // level 2: 64 rows
constexpr int E3_OFF  = 24576;      // level 3: 32 rows
constexpr int E4_OFF  = 28672;      // level 4: 16 rows
constexpr int EG_STRIDE = 30720;    // floats per batch

__device__ __forceinline__ int xoff(int l) { return 512 - (512 >> l); }   // l in 0..7
// LDS e-levels 5..8 offsets (floats): rows 8,4,2,1(+pad)
__device__ __forceinline__ int ldse(int l) {
  return (l == 5) ? 0 : (l == 6) ? 1024 : (l == 7) ? 1536 : 1792;
}

// ---- one MLP chunk: eout = relu(z@W1+b1 [+lab]) @ W2 + b2 ----------------
// 8 waves x 2 passes = 16 K-slices of 16k (both layers). Per pass the wave
// preloads its whole 16-row weight slice into registers (float4 w[16] = 64
// VGPRs, 16 independent b128 loads in flight -> one latency exposure), then
// row-loops with acc = 1 float4/float2. Weights read exactly once per chunk.
// 512-thread blocks compile at 128 VGPRs (measured R9) -> ~100 live fits.
template <int C, bool ZG>
__device__ __forceinline__ void mlp_chunk(
    const float* __restrict__ zg, const float* zl, int zstr,
    const float* __restrict__ W1, const float* __restrict__ B1,
    const float* __restrict__ W2, const float* __restrict__ B2,
    const float* lab, bool uselab, const int* u1h, int done,
    float* red, float* h, float* eoutL, float* __restrict__ eoutG)
{
  const int t  = threadIdx.x;     // 0..511
  const int wv = t >> 6;          // wave 0..7
  const int ln = t & 63;
  // -------- layer-1 partials (2 passes over K) --------
  {
    const int c0 = 4 * ln;
#pragma unroll 1
    for (int pass = 0; pass < 2; ++pass) {
      const int sl = pass * 8 + wv;        // K-slice 0..15
      const int k0 = 16 * sl;
      float4 w[16];
#pragma unroll
      for (int j = 0; j < 16; ++j)
        w[j] = *reinterpret_cast<const float4*>(W1 + (k0 + j) * 256 + c0);
#pragma unroll 1
      for (int r = 0; r < C; ++r) {
        float4 z4[4];
#pragma unroll
        for (int j = 0; j < 4; ++j) {
          if (ZG) z4[j] = *reinterpret_cast<const float4*>(zg + r * zstr + k0 + 4 * j);
          else    z4[j] = *reinterpret_cast<const float4*>(zl + r * zstr + k0 + 4 * j);
        }
        float4 acc = make_float4(0.f, 0.f, 0.f, 0.f);
#pragma unroll
        for (int j = 0; j < 4; ++j) {
          acc.x = fmaf(z4[j].x, w[4*j+0].x, fmaf(z4[j].y, w[4*j+1].x,
                  fmaf(z4[j].z, w[4*j+2].x, fmaf(z4[j].w, w[4*j+3].x, acc.x))));
          acc.y = fmaf(z4[j].x, w[4*j+0].y, fmaf(z4[j].y, w[4*j+1].y,
                  fmaf(z4[j].z, w[4*j+2].y, fmaf(z4[j].w, w[4*j+3].y, acc.y))));
          acc.z = fmaf(z4[j].x, w[4*j+0].z, fmaf(z4[j].y, w[4*j+1].z,
                  fmaf(z4[j].z, w[4*j+2].z, fmaf(z4[j].w, w[4*j+3].z, acc.z))));
          acc.w = fmaf(z4[j].x, w[4*j+0].w, fmaf(z4[j].y, w[4*j+1].w,
                  fmaf(z4[j].z, w[4*j+2].w, fmaf(z4[j].w, w[4*j+3].w, acc.w))));
        }
        *reinterpret_cast<float4*>(red + (sl * C + r) * 256 + c0) = acc;
      }
    }
  }
  __syncthreads();
  // -------- layer-1 reduce + bias + lab + relu -> h --------
  if (t < 64 * C) {
    const int r  = t >> 6;
    const int c0 = 4 * (t & 63);
    float4 s = *reinterpret_cast<const float4*>(B1 + c0);
    if (uselab) {
      const int j = u1h[done + r] & 1;
      const float4 lv = *reinterpret_cast<const float4*>(lab + j * 256 + c0);
      s.x += lv.x; s.y += lv.y; s.z += lv.z; s.w += lv.w;
    }
#pragma unroll
    for (int q = 0; q < 16; ++q) {
      const float4 p = *reinterpret_cast<const float4*>(red + (q * C + r) * 256 + c0);
      s.x += p.x; s.y += p.y; s.z += p.z; s.w += p.w;
    }
    s.x = fmaxf(s.x, 0.f); s.y = fmaxf(s.y, 0.f);
    s.z = fmaxf(s.z, 0.f); s.w = fmaxf(s.w, 0.f);
    *reinterpret_cast<float4*>(h + r * 256 + c0) = s;
  }
  __syncthreads();
  // -------- layer-2 partials (2 passes over K) --------
  {
    const int c0 = 2 * ln;
#pragma unroll 1
    for (int pass = 0; pass < 2; ++pass) {
      const int sl = pass * 8 + wv;
      const int k0 = 16 * sl;
      float2 w[16];
#pragma unroll
      for (int j = 0; j < 16; ++j)
        w[j] = *reinterpret_cast<const float2*>(W2 + (k0 + j) * 128 + c0);
#pragma unroll 1
      for (int r = 0; r < C; ++r) {
        float4 h4[4];
#pragma unroll
        for (int j = 0; j < 4; ++j)
          h4[j] = *reinterpret_cast<const float4*>(h + r * 256 + k0 + 4 * j);
        float2 acc = make_float2(0.f, 0.f);
#pragma unroll
        for (int j = 0; j < 4; ++j) {
          acc.x = fmaf(h4[j].x, w[4*j+0].x, fmaf(h4[j].y, w[4*j+1].x,
                  fmaf(h4[j].z, w[4*j+2].x, fmaf(h4[j].w, w[4*j+3].x, acc.x))));
          acc.y = fmaf(h4[j].x, w[4*j+0].y, fmaf(h4[j].y, w[4*j+1].y,
                  fmaf(h4[j].z, w[4*j+2].y, fmaf(h4[j].w, w[4*j+3].y, acc.y))));
        }
        *reinterpret_cast<float2*>(red + (sl * C + r) * 128 + c0) = acc;
      }
    }
  }
  __syncthreads();
  // -------- layer-2 reduce + bias -> eout --------
  for (int idx = t; idx < 128 * C; idx += NTHR) {
    const int r = idx >> 7;
    const int c = idx & 127;
    float s = B2[c];
#pragma unroll
    for (int q = 0; q < 16; ++q) s += red[(q * C + r) * 128 + c];
    if (eoutL) eoutL[r * 128 + c] = s;
    else       eoutG[r * 128 + c] = s;
  }
  __syncthreads();
}

__global__ void sc_setup(const int* __restrict__ info_set,
                         const float* __restrict__ E_obs,
                         const float* __restrict__ E_lab,
                         const float* __restrict__ Wb1,
                         int* __restrict__ pos2k, float* __restrict__ lab1,
                         float* __restrict__ eroot)
{
  const int t = threadIdx.x;   // 256 threads
  pos2k[t] = -1;
  __syncthreads();
  if (t < 128) pos2k[info_set[t]] = t;
  eroot[t] = E_obs[2 * 128 + (t & 127)];
  for (int j = 0; j < 2; ++j) {
    float s = 0.0f;
    for (int k = 0; k < 128; ++k)
      s = fmaf(E_lab[j * 128 + k], Wb1[(256 + k) * 256 + t], s);
    lab1[j * 256 + t] = s;
  }
}

__global__ __launch_bounds__(NTHR, 1)
void sc_main(const int* __restrict__ info_bits, const float* __restrict__ rin,
             const float* __restrict__ Wc1, const float* __restrict__ bc1,
             const float* __restrict__ Wc2, const float* __restrict__ bc2,
             const float* __restrict__ Wb1, const float* __restrict__ bb1,
             const float* __restrict__ Wb2, const float* __restrict__ bb2,
             const float* __restrict__ Wl, const float* __restrict__ bl,
             const int* __restrict__ pos2k, const float* __restrict__ lab1_g,
             const float* __restrict__ eroot_g,
             float* __restrict__ wsall, float* __restrict__ out)
{
  const int b = blockIdx.x;
  const int t = threadIdx.x;
  float* eg = wsall + (size_t)b * EG_STRIDE;   // levels 1..4 (global)

  __shared__ float red[32768];      // 128 KB split-K partials
  __shared__ float h_lds[2048];     //   8 KB hidden
  __shared__ float e_lds[2048];     //   8 KB e-levels 5..8 (+pad)
  __shared__ float lab_lds[512];
  __shared__ float eroot[256];
  __shared__ int   xh[520];         // +8 pad (padded-row u1h reads)

  for (int idx = t; idx < 512; idx += NTHR) lab_lds[idx] = lab1_g[idx];
  if (t < 256) eroot[t] = eroot_g[t];
  if (t >= 256 && t < 264) xh[256 + t] = 0;   // pad init (entries 512..519)
  __syncthreads();

  float* xO = out;
  float* fO = out + 32768;
  float* uO = out + 65536;
  float* pO = out + 98304;
  float* rO = out + 131072;

  auto run_level = [&](int l, bool isbit) {
    const int rows = 128 >> l;
    const float* W1 = isbit ? Wb1 : Wc1;
    const float* B1 = isbit ? bb1 : bc1;
    const float* W2 = isbit ? Wb2 : Wc2;
    const float* B2 = isbit ? bb2 : bc2;
    const int* u1h = xh + xoff(l);
    const float* zg = nullptr; const float* zl = nullptr;
    int zstr = 256; bool isZG = false;
    float* eoL = nullptr; float* eoG = nullptr;
    switch (l) {
      case 0: zl = eroot; zstr = 0;            eoG = eg + E1_OFF; break;
      case 1: zg = eg + E1_OFF; isZG = true;   eoG = eg + E2_OFF; break;
      case 2: zg = eg + E2_OFF; isZG = true;   eoG = eg + E3_OFF; break;
      case 3: zg = eg + E3_OFF; isZG = true;   eoG = eg + E4_OFF; break;
      case 4: zg = eg + E4_OFF; isZG = true;   eoL = e_lds + ldse(5); break;
      case 5: zl = e_lds + ldse(5);            eoL = e_lds + ldse(6); break;
      case 6: zl = e_lds + ldse(6);            eoL = e_lds + ldse(7); break;
      default: zl = e_lds + ldse(7);           eoL = e_lds + ldse(8); break;
    }
    int done = 0;
    while (done < rows) {
      int c = rows - done;
      if (c > 8) c = 8;
      const float* zgc = zg ? zg + done * zstr : nullptr;
      const float* zlc = zl ? zl + done * zstr : nullptr;
      float* eoLc = eoL ? eoL + done * 128 : nullptr;
      float* eoGc = eoG ? eoG + done * 128 : nullptr;
      if (c == 8) {
        if (isZG) mlp_chunk<8, true >(zgc, zlc, zstr, W1, B1, W2, B2, lab_lds, isbit, u1h, done, red, h_lds, eoLc, eoGc);
        else      mlp_chunk<8, false>(zgc, zlc, zstr, W1, B1, W2, B2, lab_lds, isbit, u1h, done, red, h_lds, eoLc, eoGc);
      } else if (c == 4) {
        if (isZG) mlp_chunk<4, true >(zgc, zlc, zstr, W1, B1, W2, B2, lab_lds, isbit, u1h, done, red, h_lds, eoLc, eoGc);
        else      mlp_chunk<4, false>(zgc, zlc, zstr, W1, B1, W2, B2, lab_lds, isbit, u1h, done, red, h_lds, eoLc, eoGc);
      } else {    // c == 2 or 1 -> padded C=2
        if (isZG) mlp_chunk<2, true >(zgc, zlc, zstr, W1, B1, W2, B2, lab_lds, isbit, u1h, done, red, h_lds, eoLc, eoGc);
        else      mlp_chunk<2, false>(zgc, zlc, zstr, W1, B1, W2, B2, lab_lds, isbit, u1h, done, red, h_lds, eoLc, eoGc);
      }
      done += c;
    }
  };

  auto do_leaf = [&](int i) {
    const float* e = e_lds + ldse(8);
    if (t < 64) {
      float partial = e[t] * Wl[t] + e[t + 64] * Wl[t + 64];
#pragma unroll
      for (int m = 32; m >= 1; m >>= 1) partial += __shfl_xor(partial, m);
      if (t == 0) {
        const float tv = partial + bl[0];
        const float p  = 1.0f / (1.0f + expf(-tv));
        const float rv = rin[b * 256 + i];
        const int  hd     = (rv > p) ? 1 : 0;
        const bool frozen = fabsf(p - 0.5f) > 0.25f;
        const int  k  = pos2k[i];
        const int  fc = (k >= 0) ? info_bits[b * 128 + k] : 2;
        const int  x  = (fc == 2 || frozen) ? hd : fc;
        xh[xoff(7) + (i & 1)] = x;
        pO[b * 256 + i] = p;
        uO[b * 256 + i] = (float)x;
        fO[b * 256 + i] = (k >= 0) ? 2.0f : 1.0f;
        rO[b * 256 + i] = rv;
      }
    }
    __syncthreads();
  };
  auto do_combine = [&](int l, int side) {
    const int n = 256 >> l, half = n >> 1;
    if (t < half) {
      const int u1 = xh[xoff(l) + t];
      const int u2 = xh[xoff(l) + half + t];
      if (l > 0) {
        const int base = xoff(l - 1) + side * n;
        xh[base + 2 * t]     = u1 ^ u2;
        xh[base + 2 * t + 1] = u2;
      } else {
        xO[b * 256 + 2 * t]     = (float)(u1 ^ u2);
        xO[b * 256 + 2 * t + 1] = (float)u2;
      }
    }
    __syncthreads();
  };

  // ---- SC traversal, single stage call-site ----
  int i = 0, l = 0;
  bool isbit = false;
  while (true) {
    run_level(l, isbit);
    if (l < 7) { ++l; isbit = false; continue; }
    do_leaf(i);
    if (i == 255) break;
    ++i;
    const int s = __builtin_ctz(i);
    for (int j = 1; j <= s; ++j) do_combine(8 - j, (j < s) ? 1 : 0);
    l = 7 - s;
    isbit = true;
  }
  for (int j = 1; j <= 8; ++j) do_combine(8 - j, 1);
}

extern "C" void kernel_launch(void* const* d_in, const int* in_sizes, int n_in,
                              void* d_out, int out_size, void* d_ws, size_t ws_size,
                              hipStream_t stream)
{
  const int*   info_bits = (const int*)  d_in[0];
  const float* rin       = (const float*)d_in[1];
  const int*   info_set  = (const int*)  d_in[2];
  const float* E_obs     = (const float*)d_in[3];
  const float* E_lab     = (const float*)d_in[4];
  const float* Wc1 = (const float*)d_in[5];
  const float* bc1 = (const float*)d_in[6];
  const float* Wc2 = (const float*)d_in[7];
  const float* bc2 = (const float*)d_in[8];
  const float* Wb1 = (const float*)d_in[9];
  const float* bb1 = (const float*)d_in[10];
  const float* Wb2 = (const float*)d_in[11];
  const float* bb2 = (const float*)d_in[12];
  const float* Wl  = (const float*)d_in[13];
  const float* bl  = (const float*)d_in[14];

  int*   pos2k = (int*)d_ws;                 // 256 ints
  float* lab1  = (float*)d_ws + 256;         // 512 floats
  float* eroot = (float*)d_ws + 768;         // 256 floats
  float* wsall = (float*)d_ws + 1024;        // 128 x EG_STRIDE floats

  hipLaunchKernelGGL(sc_setup, dim3(1), dim3(256), 0, stream,
                     info_set, E_obs, E_lab, Wb1, pos2k, lab1, eroot);
  hipLaunchKernelGGL(sc_main, dim3(128), dim3(NTHR), 0, stream,
                     info_bits, rin,
                     Wc1, bc1, Wc2, bc2, Wb1, bb1, Wb2, bb2, Wl, bl,
                     pos2k, lab1, eroot, wsall, (float*)d_out);
}

// Round 12
// 4553.928 us; speedup vs baseline: 4.6499x; 1.0088x over previous
//
#include <hip/hip_runtime.h>
#include <math.h>

#define NTHR 1024

// per-batch global e-buffers (floats)
constexpr int E1_OFF  = 0;          // level 1: 128 rows x 128
constexpr int E2_OFF  = 16384;      // level 2: 64 rows
constexpr int E3_OFF  = 24576;      // level 3: 32 rows
constexpr int E4_OFF  = 28672;      // level 4: 16 rows
constexpr int EG_STRIDE = 30720;    // floats per batch

__device__ __forceinline__ int xoff(int l) { return 512 - (512 >> l); }   // l in 0..7
// LDS e-levels 5..8 offsets (floats): rows 8,4,2,1(+pad)
__device__ __forceinline__ int ldse(int l) {
  return (l == 5) ? 0 : (l == 6) ? 1024 : (l == 7) ? 1536 : 1792;
}

// ---- one MLP chunk: eout = relu(z@W1+b1 [+lab]) @ W2 + b2 ----------------
// 16 waves = 16 K-slices of 16k, each run as 2 half-passes of 8k with
// float4 w[8] preloaded (32 VGPRs, 8 independent b128 loads in flight).
// 1024-thread blocks compile at the 64-VGPR cap (measured R7/R10); live set
// here ~56 regs -> no spill, 4 waves/SIMD for burst interleaving.
// Half-pass 1 folds into the same red slot via thread-local LDS rmw.
template <int C, bool ZG>
__device__ __forceinline__ void mlp_chunk(
    const float* __restrict__ zg, const float* zl, int zstr,
    const float* __restrict__ W1, const float* __restrict__ B1,
    const float* __restrict__ W2, const float* __restrict__ B2,
    const float* lab, bool uselab, const int* u1h, int done,
    float* red, float* h, float* eoutL, float* __restrict__ eoutG)
{
  const int t  = threadIdx.x;
  const int wv = t >> 6;          // K-slice 0..15  (k in [16wv,16wv+16))
  const int ln = t & 63;
  // -------- layer-1 partials: 2 half-passes of 8k --------
  {
    const int c0 = 4 * ln;
#pragma unroll 1
    for (int hp = 0; hp < 2; ++hp) {
      const int kh = 16 * wv + 8 * hp;
      float4 w[8];
#pragma unroll
      for (int j = 0; j < 8; ++j)
        w[j] = *reinterpret_cast<const float4*>(W1 + (kh + j) * 256 + c0);
#pragma unroll 1
      for (int r = 0; r < C; ++r) {
        float4 za, zb;
        if (ZG) { za = *reinterpret_cast<const float4*>(zg + r * zstr + kh);
                  zb = *reinterpret_cast<const float4*>(zg + r * zstr + kh + 4); }
        else    { za = *reinterpret_cast<const float4*>(zl + r * zstr + kh);
                  zb = *reinterpret_cast<const float4*>(zl + r * zstr + kh + 4); }
        float4 acc = make_float4(0.f, 0.f, 0.f, 0.f);
        acc.x = fmaf(za.x, w[0].x, fmaf(za.y, w[1].x, fmaf(za.z, w[2].x, fmaf(za.w, w[3].x, acc.x))));
        acc.y = fmaf(za.x, w[0].y, fmaf(za.y, w[1].y, fmaf(za.z, w[2].y, fmaf(za.w, w[3].y, acc.y))));
        acc.z = fmaf(za.x, w[0].z, fmaf(za.y, w[1].z, fmaf(za.z, w[2].z, fmaf(za.w, w[3].z, acc.z))));
        acc.w = fmaf(za.x, w[0].w, fmaf(za.y, w[1].w, fmaf(za.z, w[2].w, fmaf(za.w, w[3].w, acc.w))));
        acc.x = fmaf(zb.x, w[4].x, fmaf(zb.y, w[5].x, fmaf(zb.z, w[6].x, fmaf(zb.w, w[7].x, acc.x))));
        acc.y = fmaf(zb.x, w[4].y, fmaf(zb.y, w[5].y, fmaf(zb.z, w[6].y, fmaf(zb.w, w[7].y, acc.y))));
        acc.z = fmaf(zb.x, w[4].z, fmaf(zb.y, w[5].z, fmaf(zb.z, w[6].z, fmaf(zb.w, w[7].z, acc.z))));
        acc.w = fmaf(zb.x, w[4].w, fmaf(zb.y, w[5].w, fmaf(zb.z, w[6].w, fmaf(zb.w, w[7].w, acc.w))));
        float* slot = red + (wv * C + r) * 256 + c0;
        if (hp == 0) {
          *reinterpret_cast<float4*>(slot) = acc;
        } else {
          float4 p = *reinterpret_cast<const float4*>(slot);
          p.x += acc.x; p.y += acc.y; p.z += acc.z; p.w += acc.w;
          *reinterpret_cast<float4*>(slot) = p;
        }
      }
    }
  }
  __syncthreads();
  // -------- layer-1 reduce + bias + lab + relu -> h --------
  if (t < 64 * C) {
    const int r  = t >> 6;
    const int c0 = 4 * (t & 63);
    float4 s = *reinterpret_cast<const float4*>(B1 + c0);
    if (uselab) {
      const int j = u1h[done + r] & 1;
      const float4 lv = *reinterpret_cast<const float4*>(lab + j * 256 + c0);
      s.x += lv.x; s.y += lv.y; s.z += lv.z; s.w += lv.w;
    }
#pragma unroll
    for (int q = 0; q < 16; ++q) {
      const float4 p = *reinterpret_cast<const float4*>(red + (q * C + r) * 256 + c0);
      s.x += p.x; s.y += p.y; s.z += p.z; s.w += p.w;
    }
    s.x = fmaxf(s.x, 0.f); s.y = fmaxf(s.y, 0.f);
    s.z = fmaxf(s.z, 0.f); s.w = fmaxf(s.w, 0.f);
    *reinterpret_cast<float4*>(h + r * 256 + c0) = s;
  }
  __syncthreads();
  // -------- layer-2 partials: 2 half-passes of 8k --------
  {
    const int c0 = 2 * ln;
#pragma unroll 1
    for (int hp = 0; hp < 2; ++hp) {
      const int kh = 16 * wv + 8 * hp;
      float2 w[8];
#pragma unroll
      for (int j = 0; j < 8; ++j)
        w[j] = *reinterpret_cast<const float2*>(W2 + (kh + j) * 128 + c0);
#pragma unroll 1
      for (int r = 0; r < C; ++r) {
        const float4 ha = *reinterpret_cast<const float4*>(h + r * 256 + kh);
        const float4 hb = *reinterpret_cast<const float4*>(h + r * 256 + kh + 4);
        float2 acc = make_float2(0.f, 0.f);
        acc.x = fmaf(ha.x, w[0].x, fmaf(ha.y, w[1].x, fmaf(ha.z, w[2].x, fmaf(ha.w, w[3].x, acc.x))));
        acc.y = fmaf(ha.x, w[0].y, fmaf(ha.y, w[1].y, fmaf(ha.z, w[2].y, fmaf(ha.w, w[3].y, acc.y))));
        acc.x = fmaf(hb.x, w[4].x, fmaf(hb.y, w[5].x, fmaf(hb.z, w[6].x, fmaf(hb.w, w[7].x, acc.x))));
        acc.y = fmaf(hb.x, w[4].y, fmaf(hb.y, w[5].y, fmaf(hb.z, w[6].y, fmaf(hb.w, w[7].y, acc.y))));
        float* slot = red + (wv * C + r) * 128 + c0;
        if (hp == 0) {
          *reinterpret_cast<float2*>(slot) = acc;
        } else {
          float2 p = *reinterpret_cast<const float2*>(slot);
          p.x += acc.x; p.y += acc.y;
          *reinterpret_cast<float2*>(slot) = p;
        }
      }
    }
  }
  __syncthreads();
  // -------- layer-2 reduce + bias -> eout --------
  if (t < 128 * C) {
    const int r = t >> 7;
    const int c = t & 127;
    float s = B2[c];
#pragma unroll
    for (int q = 0; q < 16; ++q) s += red[(q * C + r) * 128 + c];
    if (eoutL) eoutL[r * 128 + c] = s;
    else       eoutG[r * 128 + c] = s;
  }
  __syncthreads();
}

__global__ void sc_setup(const int* __restrict__ info_set,
                         const float* __restrict__ E_obs,
                         const float* __restrict__ E_lab,
                         const float* __restrict__ Wb1,
                         int* __restrict__ pos2k, float* __restrict__ lab1,
                         float* __restrict__ eroot)
{
  const int t = threadIdx.x;   // 256 threads
  pos2k[t] = -1;
  __syncthreads();
  if (t < 128) pos2k[info_set[t]] = t;
  eroot[t] = E_obs[2 * 128 + (t & 127)];
  for (int j = 0; j < 2; ++j) {
    float s = 0.0f;
    for (int k = 0; k < 128; ++k)
      s = fmaf(E_lab[j * 128 + k], Wb1[(256 + k) * 256 + t], s);
    lab1[j * 256 + t] = s;
  }
}

__global__ __launch_bounds__(NTHR)
void sc_main(const int* __restrict__ info_bits, const float* __restrict__ rin,
             const float* __restrict__ Wc1, const float* __restrict__ bc1,
             const float* __restrict__ Wc2, const float* __restrict__ bc2,
             const float* __restrict__ Wb1, const float* __restrict__ bb1,
             const float* __restrict__ Wb2, const float* __restrict__ bb2,
             const float* __restrict__ Wl, const float* __restrict__ bl,
             const int* __restrict__ pos2k, const float* __restrict__ lab1_g,
             const float* __restrict__ eroot_g,
             float* __restrict__ wsall, float* __restrict__ out)
{
  const int b = blockIdx.x;
  const int t = threadIdx.x;
  float* eg = wsall + (size_t)b * EG_STRIDE;   // levels 1..4 (global)

  __shared__ float red[32768];      // 128 KB split-K partials (16 slices)
  __shared__ float h_lds[2048];     //   8 KB hidden
  __shared__ float e_lds[2048];     //   8 KB e-levels 5..8 (+pad)
  __shared__ float lab_lds[512];
  __shared__ float eroot[256];
  __shared__ int   xh[520];         // +8 pad (padded-row u1h reads)

  for (int idx = t; idx < 512; idx += NTHR) lab_lds[idx] = lab1_g[idx];
  if (t < 256) eroot[t] = eroot_g[t];
  if (t >= 512 && t < 520) xh[t] = 0;
  __syncthreads();

  float* xO = out;
  float* fO = out + 32768;
  float* uO = out + 65536;
  float* pO = out + 98304;
  float* rO = out + 131072;

  auto run_level = [&](int l, bool isbit) {
    const int rows = 128 >> l;
    const float* W1 = isbit ? Wb1 : Wc1;
    const float* B1 = isbit ? bb1 : bc1;
    const float* W2 = isbit ? Wb2 : Wc2;
    const float* B2 = isbit ? bb2 : bc2;
    const int* u1h = xh + xoff(l);
    const float* zg = nullptr; const float* zl = nullptr;
    int zstr = 256; bool isZG = false;
    float* eoL = nullptr; float* eoG = nullptr;
    switch (l) {
      case 0: zl = eroot; zstr = 0;            eoG = eg + E1_OFF; break;
      case 1: zg = eg + E1_OFF; isZG = true;   eoG = eg + E2_OFF; break;
      case 2: zg = eg + E2_OFF; isZG = true;   eoG = eg + E3_OFF; break;
      case 3: zg = eg + E3_OFF; isZG = true;   eoG = eg + E4_OFF; break;
      case 4: zg = eg + E4_OFF; isZG = true;   eoL = e_lds + ldse(5); break;
      case 5: zl = e_lds + ldse(5);            eoL = e_lds + ldse(6); break;
      case 6: zl = e_lds + ldse(6);            eoL = e_lds + ldse(7); break;
      default: zl = e_lds + ldse(7);           eoL = e_lds + ldse(8); break;
    }
    int done = 0;
    while (done < rows) {
      int c = rows - done;
      if (c > 8) c = 8;
      const float* zgc = zg ? zg + done * zstr : nullptr;
      const float* zlc = zl ? zl + done * zstr : nullptr;
      float* eoLc = eoL ? eoL + done * 128 : nullptr;
      float* eoGc = eoG ? eoG + done * 128 : nullptr;
      if (c == 8) {
        if (isZG) mlp_chunk<8, true >(zgc, zlc, zstr, W1, B1, W2, B2, lab_lds, isbit, u1h, done, red, h_lds, eoLc, eoGc);
        else      mlp_chunk<8, false>(zgc, zlc, zstr, W1, B1, W2, B2, lab_lds, isbit, u1h, done, red, h_lds, eoLc, eoGc);
      } else if (c == 4) {
        if (isZG) mlp_chunk<4, true >(zgc, zlc, zstr, W1, B1, W2, B2, lab_lds, isbit, u1h, done, red, h_lds, eoLc, eoGc);
        else      mlp_chunk<4, false>(zgc, zlc, zstr, W1, B1, W2, B2, lab_lds, isbit, u1h, done, red, h_lds, eoLc, eoGc);
      } else {    // c == 2 or 1 -> padded C=2
        if (isZG) mlp_chunk<2, true >(zgc, zlc, zstr, W1, B1, W2, B2, lab_lds, isbit, u1h, done, red, h_lds, eoLc, eoGc);
        else      mlp_chunk<2, false>(zgc, zlc, zstr, W1, B1, W2, B2, lab_lds, isbit, u1h, done, red, h_lds, eoLc, eoGc);
      }
      done += c;
    }
  };

  auto do_leaf = [&](int i) {
    const float* e = e_lds + ldse(8);
    if (t < 64) {
      float partial = e[t] * Wl[t] + e[t + 64] * Wl[t + 64];
#pragma unroll
      for (int m = 32; m >= 1; m >>= 1) partial += __shfl_xor(partial, m);
      if (t == 0) {
        const float tv = partial + bl[0];
        const float p  = 1.0f / (1.0f + expf(-tv));
        const float rv = rin[b * 256 + i];
        const int  hd     = (rv > p) ? 1 : 0;
        const bool frozen = fabsf(p - 0.5f) > 0.25f;
        const int  k  = pos2k[i];
        const int  fc = (k >= 0) ? info_bits[b * 128 + k] : 2;
        const int  x  = (fc == 2 || frozen) ? hd : fc;
        xh[xoff(7) + (i & 1)] = x;
        pO[b * 256 + i] = p;
        uO[b * 256 + i] = (float)x;
        fO[b * 256 + i] = (k >= 0) ? 2.0f : 1.0f;
        rO[b * 256 + i] = rv;
      }
    }
    __syncthreads();
  };
  auto do_combine = [&](int l, int side) {
    const int n = 256 >> l, half = n >> 1;
    if (t < half) {
      const int u1 = xh[xoff(l) + t];
      const int u2 = xh[xoff(l) + half + t];
      if (l > 0) {
        const int base = xoff(l - 1) + side * n;
        xh[base + 2 * t]     = u1 ^ u2;
        xh[base + 2 * t + 1] = u2;
      } else {
        xO[b * 256 + 2 * t]     = (float)(u1 ^ u2);
        xO[b * 256 + 2 * t + 1] = (float)u2;
      }
    }
    __syncthreads();
  };

  // ---- SC traversal, single stage call-site ----
  int i = 0, l = 0;
  bool isbit = false;
  while (true) {
    run_level(l, isbit);
    if (l < 7) { ++l; isbit = false; continue; }
    do_leaf(i);
    if (i == 255) break;
    ++i;
    const int s = __builtin_ctz(i);
    for (int j = 1; j <= s; ++j) do_combine(8 - j, (j < s) ? 1 : 0);
    l = 7 - s;
    isbit = true;
  }
  for (int j = 1; j <= 8; ++j) do_combine(8 - j, 1);
}

extern "C" void kernel_launch(void* const* d_in, const int* in_sizes, int n_in,
                              void* d_out, int out_size, void* d_ws, size_t ws_size,
                              hipStream_t stream)
{
  const int*   info_bits = (const int*)  d_in[0];
  const float* rin       = (const float*)d_in[1];
  const int*   info_set  = (const int*)  d_in[2];
  const float* E_obs     = (const float*)d_in[3];
  const float* E_lab     = (const float*)d_in[4];
  const float* Wc1 = (const float*)d_in[5];
  const float* bc1 = (const float*)d_in[6];
  const float* Wc2 = (const float*)d_in[7];
  const float* bc2 = (const float*)d_in[8];
  const float* Wb1 = (const float*)d_in[9];
  const float* bb1 = (const float*)d_in[10];
  const float* Wb2 = (const float*)d_in[11];
  const float* bb2 = (const float*)d_in[12];
  const float* Wl  = (const float*)d_in[13];
  const float* bl  = (const float*)d_in[14];

  int*   pos2k = (int*)d_ws;                 // 256 ints
  float* lab1  = (float*)d_ws + 256;         // 512 floats
  float* eroot = (float*)d_ws + 768;         // 256 floats
  float* wsall = (float*)d_ws + 1024;        // 128 x EG_STRIDE floats

  hipLaunchKernelGGL(sc_setup, dim3(1), dim3(256), 0, stream,
                     info_set, E_obs, E_lab, Wb1, pos2k, lab1, eroot);
  hipLaunchKernelGGL(sc_main, dim3(128), dim3(NTHR), 0, stream,
                     info_bits, rin,
                     Wc1, bc1, Wc2, bc2, Wb1, bb1, Wb2, bb2, Wl, bl,
                     pos2k, lab1, eroot, wsall, (float*)d_out);
}